// Round 7
// baseline (203.741 us; speedup 1.0000x reference)
//
#include <hip/hip_runtime.h>
#include <math.h>

#define B_ 64
#define N_ 512
#define DIM_ 128
#define E_ 16
#define G_ 32
#define TOPK_ 4
#define HID_ 512

constexpr int BN_ROWS = B_ * N_;  // 32768

using bf16x8 = __attribute__((ext_vector_type(8))) short;
using s16x4  = __attribute__((ext_vector_type(4))) short;
using f32x4  = __attribute__((ext_vector_type(4))) float;

__device__ __forceinline__ float bf2f(short s) {
    union { unsigned u; float f; } x;
    x.u = ((unsigned)(unsigned short)s) << 16;
    return x.f;
}
__device__ __forceinline__ short f2bf(float f) {
    union { float f; unsigned u; } x;
    x.f = f;
    unsigned r = x.u + 0x7FFF + ((x.u >> 16) & 1);  // RNE
    return (short)(r >> 16);
}

// read one MFMA fragment (8 bf16, 16B) from a [rows][64] bf16 LDS tile with XOR swizzle
__device__ __forceinline__ bf16x8 frag_ld(const short* base, int row, int ks, int lhi) {
    int addr = row * 128 + (((ks * 64) + lhi * 16) ^ ((row & 7) << 4));
    return *(const bf16x8*)((const char*)base + addr);
}

// async global->LDS, 16B per lane; LDS dest = wave-uniform base + lane*16
typedef __attribute__((address_space(3))) void lds_vt;
typedef __attribute__((address_space(1))) const void gbl_vt;
__device__ __forceinline__ void gl2lds(const void* g, void* l) {
    __builtin_amdgcn_global_load_lds((gbl_vt*)g, (lds_vt*)l, 16, 0, 0);
}
__device__ __forceinline__ void vm0_bar() {
    asm volatile("s_waitcnt vmcnt(0)" ::: "memory");
    __builtin_amdgcn_sched_barrier(0);
    __builtin_amdgcn_s_barrier();
    __builtin_amdgcn_sched_barrier(0);
}
__device__ __forceinline__ void lgkm0_bar() {
    asm volatile("s_waitcnt lgkmcnt(0)" ::: "memory");
    __builtin_amdgcn_sched_barrier(0);
    __builtin_amdgcn_s_barrier();
    __builtin_amdgcn_sched_barrier(0);
}

// ================= k_misc: all preprocessing in ONE launch, grid-sectioned =================
constexpr int NPRE = BN_ROWS / 4;     // 8192: fused rmsnorm+route (4 rows/block)
constexpr int NXNT = B_ * 16;         // 1024: fused rmsnorm+transpose -> xnT bf16
constexpr int NSMG = 32 * 512 / 8;    // 2048: softmax over G
constexpr int NSMN = 1024 / 4;        // 256: softmax over N
constexpr int NTW  = 64 * 3;          // 192: weight transposes
constexpr int NMISC = NPRE + NXNT + NSMG + NSMN + NTW + 1;  // +1 lambda

__global__ __launch_bounds__(256) void k_misc(
    const float* __restrict__ x, const float* __restrict__ attn_s,
    const float* __restrict__ Wr, const float* __restrict__ br, const float* __restrict__ bias,
    float* __restrict__ route, float* __restrict__ topk_out,
    short* __restrict__ xnT,
    const float* __restrict__ E1, short* __restrict__ A1nb,
    const float* __restrict__ E2, short* __restrict__ A2nb,
    const float* __restrict__ W1, const float* __restrict__ W2, const float* __restrict__ W3,
    short* __restrict__ W1T, short* __restrict__ W2T, short* __restrict__ W3T,
    const float* __restrict__ lq1, const float* __restrict__ lk1,
    const float* __restrict__ lq2, const float* __restrict__ lk2,
    float lam_init, float* __restrict__ lam_out) {
    __shared__ float tb[32][129];
    __shared__ float invb[32];
    __shared__ float tw[32][33];
    int blk = blockIdx.x;
    int tid = threadIdx.x;

    if (blk < NPRE) {  // ---- fused rmsnorm + route (shfl GEMV + rank top-k): wave = one row ----
        int w = tid >> 6, lane = tid & 63;
        int row = blk * 4 + w;
        float2 v = ((const float2*)(x + (size_t)row * DIM_))[lane];
        float ss = v.x * v.x + v.y * v.y;
        for (int off = 32; off; off >>= 1) ss += __shfl_xor(ss, off);
        float inv = 1.0f / (sqrtf(ss * (1.0f / DIM_)) + 1e-8f);
        float2 s = ((const float2*)attn_s)[lane];
        float xn0 = v.x * inv * s.x;   // element d = 2*lane
        float xn1 = v.y * inv * s.y;   // element d = 2*lane+1
        int e = lane & 15, chunk = lane >> 4;
        float acc = 0.f;
#pragma unroll
        for (int j = 0; j < 16; ++j) {
            int srcl = chunk * 16 + j;
            float a0 = __shfl(xn0, srcl);
            float a1 = __shfl(xn1, srcl);
            int d0 = chunk * 32 + 2 * j;
            acc += a0 * Wr[d0 * E_ + e] + a1 * Wr[(d0 + 1) * E_ + e];
        }
        acc += __shfl_xor(acc, 16);
        acc += __shfl_xor(acc, 32);
        float gate = 1.0f / (1.0f + expf(-(acc + br[e])));
        float vv = gate + bias[0];
        // rank_e = #{i : v_i > v_e} + #{i < e : v_i == v_e}  (== lax.top_k, ties -> lower idx)
        int rank = 0;
#pragma unroll
        for (int i = 0; i < 16; ++i) {
            float vi = __shfl(vv, i);
            rank += ((vi > vv) || (vi == vv && i < e)) ? 1 : 0;
        }
        bool selq = (rank < TOPK_) && (lane < 16);
        float contrib = selq ? gate : 0.f;
        float ssum = contrib;
        ssum += __shfl_xor(ssum, 1); ssum += __shfl_xor(ssum, 2);
        ssum += __shfl_xor(ssum, 4); ssum += __shfl_xor(ssum, 8);
        if (lane < 16) route[(size_t)row * E_ + e] = selq ? gate / ssum : 0.0f;
        if (selq) topk_out[(size_t)row * TOPK_ + rank] = (float)e;
        return;
    }
    blk -= NPRE;

    if (blk < NXNT) {  // ---- fused rmsnorm + transpose: xnT[b][c][j] bf16 ----
        int b = blk >> 4, j0 = (blk & 15) * 32;
        const float* src = x + (size_t)(b * 512 + j0) * 128;
        int r = tid >> 3, c8 = tid & 7;
#pragma unroll
        for (int it = 0; it < 4; ++it) {
            int c4 = c8 + it * 8;
            float4 w4 = *(const float4*)(src + (size_t)r * 128 + c4 * 4);
            tb[r][c4 * 4 + 0] = w4.x; tb[r][c4 * 4 + 1] = w4.y;
            tb[r][c4 * 4 + 2] = w4.z; tb[r][c4 * 4 + 3] = w4.w;
        }
        __syncthreads();
        int sg = tid & 7;
        float ps = 0.f;
#pragma unroll
        for (int j = 0; j < 16; ++j) { float e2 = tb[r][sg * 16 + j]; ps += e2 * e2; }
        ps += __shfl_xor(ps, 1); ps += __shfl_xor(ps, 2); ps += __shfl_xor(ps, 4);
        if (sg == 0) invb[r] = 1.0f / (sqrtf(ps * (1.0f / DIM_)) + 1e-8f);
        __syncthreads();
        int c = tid >> 1, half = tid & 1;
        float sc = attn_s[c];
        short ov[16];
#pragma unroll
        for (int j = 0; j < 16; ++j) {
            int jj = half * 16 + j;
            ov[j] = f2bf(tb[jj][c] * invb[jj] * sc);
        }
        short* dst = xnT + (size_t)(b * 128 + c) * 512 + j0 + half * 16;
        *(bf16x8*)dst = *(bf16x8*)ov;
        *(bf16x8*)(dst + 8) = *(bf16x8*)(ov + 8);
        return;
    }
    blk -= NXNT;

    if (blk < NSMG) {  // ---- softmax over G=32 -> bf16 ----
        int row = blk * 8 + (tid >> 5);
        int l = tid & 31;
        float v = E1[(size_t)row * 32 + l];
        float m = v;
        for (int off = 16; off; off >>= 1) m = fmaxf(m, __shfl_xor(m, off));
        float ev = expf(v - m);
        float s = ev;
        for (int off = 16; off; off >>= 1) s += __shfl_xor(s, off);
        A1nb[(size_t)row * 32 + l] = f2bf(ev / s);
        return;
    }
    blk -= NSMG;

    if (blk < NSMN) {  // ---- softmax over N=512 -> bf16 ----
        int row = blk * 4 + (tid >> 6);
        int l = tid & 63;
        const float* p = E2 + (size_t)row * 512;
        float v[8];
        float m = -1e30f;
#pragma unroll
        for (int j = 0; j < 8; ++j) { v[j] = p[l + j * 64]; m = fmaxf(m, v[j]); }
        for (int off = 32; off; off >>= 1) m = fmaxf(m, __shfl_xor(m, off));
        float s = 0.f;
#pragma unroll
        for (int j = 0; j < 8; ++j) { v[j] = expf(v[j] - m); s += v[j]; }
        for (int off = 32; off; off >>= 1) s += __shfl_xor(s, off);
        float inv = 1.0f / s;
        short* q = A2nb + (size_t)row * 512;
#pragma unroll
        for (int j = 0; j < 8; ++j) q[l + j * 64] = f2bf(v[j] * inv);
        return;
    }
    blk -= NSMN;

    if (blk < NTW) {  // ---- weight transposes -> bf16 [C][R] ----
        int m = blk >> 6, tile = blk & 63;
        const float* S = (m == 0) ? W1 : (m == 1) ? W2 : W3;
        short* D = (m == 0) ? W1T : (m == 1) ? W2T : W3T;
        int R = (m == 2) ? 512 : 128, C = (m == 2) ? 128 : 512;
        int ctiles = C / 32;
        int r0 = (tile / ctiles) * 32, c0 = (tile % ctiles) * 32;
        int tx = tid & 31, ty = tid >> 5;
#pragma unroll
        for (int r = 0; r < 4; ++r) tw[ty * 4 + r][tx] = S[(size_t)(r0 + ty * 4 + r) * C + c0 + tx];
        __syncthreads();
#pragma unroll
        for (int r = 0; r < 4; ++r) D[(size_t)(c0 + ty * 4 + r) * R + r0 + tx] = f2bf(tw[tx][ty * 4 + r]);
        return;
    }

    // ---- lambda (1 block, wave 0) ----
    if (tid < 64) {
        int l = tid;
        float s1 = lq1[l] * lk1[l] + lq1[l + 64] * lk1[l + 64];
        float s2 = lq2[l] * lk2[l] + lq2[l + 64] * lk2[l + 64];
        for (int off = 32; off; off >>= 1) {
            s1 += __shfl_xor(s1, off);
            s2 += __shfl_xor(s2, off);
        }
        if (l == 0) lam_out[0] = -(expf(s1) - expf(s2) + lam_init);
    }
}

// ================= Y-GEMM (gload_lds dbuf): YT[b][c][e*512+kd] = sum_j A2[e][kd][j]*xnT[b][c][j] =================
__global__ __launch_bounds__(256) void k_gemm_y(const short* __restrict__ A2nb,
                                                const short* __restrict__ xnT,
                                                short* __restrict__ YT) {
    alignas(16) __shared__ short As0[128 * 64];
    alignas(16) __shared__ short Bs0[128 * 64];
    alignas(16) __shared__ short As1[128 * 64];
    alignas(16) __shared__ short Bs1[128 * 64];
    int id = blockIdx.x;
    int nid = ((id & 7) << 6) + (id >> 3);   // XCD-chunked: b range per XCD
    int m0 = (nid & 3) * 128;
    int be = nid >> 2, b = be >> 1, e = be & 1;
    int tid = threadIdx.x, lane = tid & 63, wid = tid >> 6;
    int l15 = lane & 15, lhi = lane >> 4;
    int wr = wid >> 1, wc = wid & 1;
    const short* Asrc = A2nb + (size_t)e * 512 * 512 + (size_t)m0 * 512;
    const short* Bsrc = xnT + (size_t)b * 128 * 512;
    int row8 = lane >> 3;
    int chunk8 = (lane & 7) ^ row8;  // pre-swizzled source chunk (inverse of read swizzle)

    auto stage = [&](short* Ad, short* Bd, int k0) {
#pragma unroll
        for (int t = 0; t < 4; ++t) {
            int i = wid * 4 + t;
            int row = i * 8 + row8;
            gl2lds(Asrc + (size_t)row * 512 + k0 + chunk8 * 8, (char*)Ad + i * 1024);
            gl2lds(Bsrc + (size_t)row * 512 + k0 + chunk8 * 8, (char*)Bd + i * 1024);
        }
    };
    f32x4 acc[4][4] = {};
    stage(As0, Bs0, 0);
    for (int s = 0; s < 8; ++s) {
        vm0_bar();  // own loads done + all waves' loads done + prev reads done
        const short* Ac = (s & 1) ? As1 : As0;
        const short* Bc = (s & 1) ? Bs1 : Bs0;
        if (s < 7) stage((s & 1) ? As0 : As1, (s & 1) ? Bs0 : Bs1, (s + 1) * 64);
#pragma unroll
        for (int ks = 0; ks < 2; ++ks) {
            bf16x8 af[4], bfr[4];
#pragma unroll
            for (int i = 0; i < 4; ++i) af[i] = frag_ld(Ac, wr * 64 + i * 16 + l15, ks, lhi);
#pragma unroll
            for (int j = 0; j < 4; ++j) bfr[j] = frag_ld(Bc, wc * 64 + j * 16 + l15, ks, lhi);
#pragma unroll
            for (int i = 0; i < 4; ++i)
#pragma unroll
                for (int j = 0; j < 4; ++j)
                    acc[i][j] = __builtin_amdgcn_mfma_f32_16x16x32_bf16(af[i], bfr[j], acc[i][j], 0, 0, 0);
        }
    }
    short* Yb = YT + (size_t)b * 128 * 1024 + e * 512;
#pragma unroll
    for (int i = 0; i < 4; ++i) {
        int mbase = m0 + wr * 64 + i * 16 + lhi * 4;
#pragma unroll
        for (int j = 0; j < 4; ++j) {
            int n = wc * 64 + j * 16 + l15;
            s16x4 o;
#pragma unroll
            for (int q = 0; q < 4; ++q) o[q] = f2bf(acc[i][j][q]);
            *(s16x4*)(Yb + (size_t)n * 1024 + mbase) = o;
        }
    }
}

// ================= attn (B via gload_lds dbuf, A reg-staged dbuf, fused residual + FFN rmsnorm) =================
__global__ __launch_bounds__(256) void k_attn(const short* __restrict__ A1nb,
                                              const float* __restrict__ route,
                                              const short* __restrict__ YT,
                                              const float* __restrict__ x,
                                              const float* __restrict__ lam_p,
                                              const float* __restrict__ ffn_s,
                                              float* __restrict__ x1,
                                              short* __restrict__ xn2b) {
    alignas(16) __shared__ short Ab0[64 * 64];
    alignas(16) __shared__ short Ab1[64 * 64];
    alignas(16) __shared__ short Bb0[128 * 64];
    alignas(16) __shared__ short Bb1[128 * 64];
    __shared__ float ssbuf[2][64];
    int id = blockIdx.x;
    int nid = ((id & 7) << 6) + (id >> 3);   // XCD-chunked; b->XCD aligned with k_gemm_y
    int m0 = (nid & 7) * 64;
    int b = nid >> 3;
    float lam = lam_p[0];
    int tid = threadIdx.x, lane = tid & 63, wid = tid >> 6;
    int l15 = lane & 15, lhi = lane >> 4;
    int wr = wid >> 1, wc = wid & 1;
    const short* YTb = YT + (size_t)b * 128 * 1024;
    int row8 = lane >> 3;
    int chunk8 = (lane & 7) ^ row8;

    auto stageB = [&](short* Bd, int k0) {
#pragma unroll
        for (int t = 0; t < 4; ++t) {
            int i = wid * 4 + t;
            int row = i * 8 + row8;
            gl2lds(YTb + (size_t)row * 1024 + k0 + chunk8 * 8, (char*)Bd + i * 1024);
        }
    };
    auto loadA = [&](float (&rv)[2], bf16x8 (&ar)[2], int sn) {
#pragma unroll
        for (int r = 0; r < 2; ++r) {
            int idx = tid + r * 256, rowl = idx >> 3, slot = idx & 7;
            int t = sn * 2 + (slot >> 2);
            int gi = m0 + rowl;
            rv[r] = route[((size_t)b * 512 + gi) * 16 + (t & 15)] * (t >= 16 ? lam : 1.0f);
            ar[r] = *(const bf16x8*)(A1nb + ((size_t)t * 512 + gi) * 32 + (slot & 3) * 8);
        }
    };
    auto writeA = [&](short* dst, float (&rv)[2], bf16x8 (&ar)[2]) {
#pragma unroll
        for (int r = 0; r < 2; ++r) {
            int idx = tid + r * 256, rowl = idx >> 3, slot = idx & 7;
            bf16x8 o;
#pragma unroll
            for (int q = 0; q < 8; ++q) o[q] = f2bf(bf2f(ar[r][q]) * rv[r]);
            *(bf16x8*)((char*)dst + rowl * 128 + ((slot * 16) ^ ((rowl & 7) << 4))) = o;
        }
    };
    f32x4 acc[2][4] = {};
    auto compute = [&](const short* Ac, const short* Bc) {
#pragma unroll
        for (int ks = 0; ks < 2; ++ks) {
            bf16x8 af[2], bfr[4];
#pragma unroll
            for (int i = 0; i < 2; ++i) af[i] = frag_ld(Ac, wr * 32 + i * 16 + l15, ks, lhi);
#pragma unroll
            for (int j = 0; j < 4; ++j) bfr[j] = frag_ld(Bc, wc * 64 + j * 16 + l15, ks, lhi);
#pragma unroll
            for (int i = 0; i < 2; ++i)
#pragma unroll
                for (int j = 0; j < 4; ++j)
                    acc[i][j] = __builtin_amdgcn_mfma_f32_16x16x32_bf16(af[i], bfr[j], acc[i][j], 0, 0, 0);
        }
    };

    float rv0[2], rv1[2];
    bf16x8 ar0[2], ar1[2];
    stageB(Bb0, 0);
    loadA(rv0, ar0, 0);
    for (int sp = 0; sp < 8; ++sp) {
        int s = sp * 2;
        // even step: cur = 0-set
        vm0_bar();
        stageB(Bb1, (s + 1) * 64);     // s+1 <= 15 always for even s
        loadA(rv1, ar1, s + 1);
        writeA(Ab0, rv0, ar0);
        lgkm0_bar();
        compute(Ab0, Bb0);
        // odd step s+1: cur = 1-set
        vm0_bar();
        if (s + 2 < 16) {
            stageB(Bb0, (s + 2) * 64);
            loadA(rv0, ar0, s + 2);
        }
        writeA(Ab1, rv1, ar1);
        lgkm0_bar();
        compute(Ab1, Bb1);
    }
    // epilogue: residual, write x1, fused rmsnorm -> xn2b
    float x1v[2][4][4];
    float pss[2][4] = {};
#pragma unroll
    for (int i = 0; i < 2; ++i) {
        int gibase = m0 + wr * 32 + i * 16 + lhi * 4;
#pragma unroll
        for (int j = 0; j < 4; ++j) {
            int n = wc * 64 + j * 16 + l15;
#pragma unroll
            for (int q = 0; q < 4; ++q) {
                size_t off = ((size_t)b * 512 + gibase + q) * 128 + n;
                float val = acc[i][j][q] + x[off];
                x1[off] = val;
                x1v[i][j][q] = val;
                pss[i][q] += val * val;
            }
        }
    }
#pragma unroll
    for (int i = 0; i < 2; ++i)
#pragma unroll
        for (int q = 0; q < 4; ++q) {
            float p = pss[i][q];
            p += __shfl_xor(p, 1); p += __shfl_xor(p, 2);
            p += __shfl_xor(p, 4); p += __shfl_xor(p, 8);
            pss[i][q] = p;
        }
    if (l15 == 0) {
#pragma unroll
        for (int i = 0; i < 2; ++i)
#pragma unroll
            for (int q = 0; q < 4; ++q)
                ssbuf[wc][wr * 32 + i * 16 + lhi * 4 + q] = pss[i][q];
    }
    __syncthreads();
#pragma unroll
    for (int i = 0; i < 2; ++i)
#pragma unroll
        for (int q = 0; q < 4; ++q) {
            int rowl = wr * 32 + i * 16 + lhi * 4 + q;
            float ssum = ssbuf[0][rowl] + ssbuf[1][rowl];
            float inv = 1.0f / (sqrtf(ssum * (1.0f / DIM_)) + 1e-8f);
#pragma unroll
            for (int j = 0; j < 4; ++j) {
                int n = wc * 64 + j * 16 + l15;
                xn2b[((size_t)b * 512 + m0 + rowl) * 128 + n] = f2bf(x1v[i][j][q] * inv * ffn_s[n]);
            }
        }
}

// ================= FFN1 (gload_lds dbuf, fused SwiGLU) =================
__global__ __launch_bounds__(256) void k_ffn1(const short* __restrict__ xn2b,
                                              const short* __restrict__ W1T, const float* __restrict__ b1,
                                              const short* __restrict__ W2T, const float* __restrict__ b2,
                                              short* __restrict__ h) {
    alignas(16) __shared__ short As0[128 * 64];
    alignas(16) __shared__ short B10[64 * 64];
    alignas(16) __shared__ short B20[64 * 64];
    alignas(16) __shared__ short As1[128 * 64];
    alignas(16) __shared__ short B11[64 * 64];
    alignas(16) __shared__ short B21[64 * 64];
    int id = blockIdx.x;
    int nid = ((id & 7) << 8) + (id >> 3);   // XCD-chunked: m-range per XCD
    int n0 = (nid & 7) * 64;
    int m0 = (nid >> 3) * 128;
    int tid = threadIdx.x, lane = tid & 63, wid = tid >> 6;
    int l15 = lane & 15, lhi = lane >> 4;
    int wr = wid >> 1, wc = wid & 1;
    int row8 = lane >> 3;
    int chunk8 = (lane & 7) ^ row8;

    auto stage = [&](short* Ad, short* B1d, short* B2d, int k0) {
#pragma unroll
        for (int t = 0; t < 8; ++t) {
            int i = wid * 8 + t;
            if (i < 16) {
                int row = i * 8 + row8;
                gl2lds(xn2b + (size_t)(m0 + row) * 128 + k0 + chunk8 * 8, (char*)Ad + i * 1024);
            } else if (i < 24) {
                int ii = i - 16, row = ii * 8 + row8;
                gl2lds(W1T + (size_t)(n0 + row) * 128 + k0 + chunk8 * 8, (char*)B1d + ii * 1024);
            } else {
                int ii = i - 24, row = ii * 8 + row8;
                gl2lds(W2T + (size_t)(n0 + row) * 128 + k0 + chunk8 * 8, (char*)B2d + ii * 1024);
            }
        }
    };
    f32x4 acc1[4][2] = {}, acc2[4][2] = {};
    stage(As0, B10, B20, 0);
    for (int s = 0; s < 2; ++s) {
        vm0_bar();
        const short* Ac = s ? As1 : As0;
        const short* B1c = s ? B11 : B10;
        const short* B2c = s ? B21 : B20;
        if (s == 0) stage(As1, B11, B21, 64);
#pragma unroll
        for (int ks = 0; ks < 2; ++ks) {
            bf16x8 af[4], b1f[2], b2f[2];
#pragma unroll
            for (int i = 0; i < 4; ++i) af[i] = frag_ld(Ac, wr * 64 + i * 16 + l15, ks, lhi);
#pragma unroll
            for (int j = 0; j < 2; ++j) {
                b1f[j] = frag_ld(B1c, wc * 32 + j * 16 + l15, ks, lhi);
                b2f[j] = frag_ld(B2c, wc * 32 + j * 16 + l15, ks, lhi);
            }
#pragma unroll
            for (int i = 0; i < 4; ++i)
#pragma unroll
                for (int j = 0; j < 2; ++j) {
                    acc1[i][j] = __builtin_amdgcn_mfma_f32_16x16x32_bf16(af[i], b1f[j], acc1[i][j], 0, 0, 0);
                    acc2[i][j] = __builtin_amdgcn_mfma_f32_16x16x32_bf16(af[i], b2f[j], acc2[i][j], 0, 0, 0);
                }
        }
    }
    // epilogue: SwiGLU -> bf16 h-tile staged in As0 (free: last compute used As1) -> coalesced store
    __syncthreads();
#pragma unroll
    for (int i = 0; i < 4; ++i) {
        int mloc = wr * 64 + i * 16 + lhi * 4;
#pragma unroll
        for (int j = 0; j < 2; ++j) {
            int nloc = wc * 32 + j * 16 + l15;
            int n = n0 + nloc;
            float bb1 = b1[n], bb2 = b2[n];
#pragma unroll
            for (int q = 0; q < 4; ++q) {
                float a1 = acc1[i][j][q] + bb1;
                float a2 = acc2[i][j][q] + bb2;
                float hv = a1 / (1.0f + expf(-a1)) * a2;
                ((short*)As0)[(mloc + q) * 64 + nloc] = f2bf(hv);
            }
        }
    }
    __syncthreads();
#pragma unroll
    for (int r = 0; r < 4; ++r) {
        int idx = tid + r * 256;
        int row = idx >> 3, slot = idx & 7;
        *(bf16x8*)(h + (size_t)(m0 + row) * 512 + n0 + slot * 8) =
            *(const bf16x8*)((char*)As0 + row * 128 + slot * 16);
    }
}

// ================= FFN2 (gload_lds dbuf): out = x1 + h @ W3 + b3 =================
__global__ __launch_bounds__(256) void k_ffn2(const short* __restrict__ h,
                                              const short* __restrict__ W3T, const float* __restrict__ b3,
                                              const float* __restrict__ x1,
                                              float* __restrict__ out) {
    alignas(16) __shared__ short As0[64 * 64];
    alignas(16) __shared__ short Bs0[128 * 64];
    alignas(16) __shared__ short As1[64 * 64];
    alignas(16) __shared__ short Bs1[128 * 64];
    int m0 = blockIdx.x * 64;
    int tid = threadIdx.x, lane = tid & 63, wid = tid >> 6;
    int l15 = lane & 15, lhi = lane >> 4;
    int wr = wid >> 1, wc = wid & 1;
    int row8 = lane >> 3;
    int chunk8 = (lane & 7) ^ row8;

    auto stage = [&](short* Ad, short* Bd, int k0) {
#pragma unroll
        for (int t = 0; t < 6; ++t) {
            int i = wid * 6 + t;
            if (i < 8) {
                int row = i * 8 + row8;
                gl2lds(h + (size_t)(m0 + row) * 512 + k0 + chunk8 * 8, (char*)Ad + i * 1024);
            } else {
                int ii = i - 8, row = ii * 8 + row8;
                gl2lds(W3T + (size_t)row * 512 + k0 + chunk8 * 8, (char*)Bd + ii * 1024);
            }
        }
    };
    f32x4 acc[2][4] = {};
    stage(As0, Bs0, 0);
    for (int s = 0; s < 8; ++s) {
        vm0_bar();
        const short* Ac = (s & 1) ? As1 : As0;
        const short* Bc = (s & 1) ? Bs1 : Bs0;
        if (s < 7) stage((s & 1) ? As0 : As1, (s & 1) ? Bs0 : Bs1, (s + 1) * 64);
#pragma unroll
        for (int ks = 0; ks < 2; ++ks) {
            bf16x8 af[2], bfr[4];
#pragma unroll
            for (int i = 0; i < 2; ++i) af[i] = frag_ld(Ac, wr * 32 + i * 16 + l15, ks, lhi);
#pragma unroll
            for (int j = 0; j < 4; ++j) bfr[j] = frag_ld(Bc, wc * 64 + j * 16 + l15, ks, lhi);
#pragma unroll
            for (int i = 0; i < 2; ++i)
#pragma unroll
                for (int j = 0; j < 4; ++j)
                    acc[i][j] = __builtin_amdgcn_mfma_f32_16x16x32_bf16(af[i], bfr[j], acc[i][j], 0, 0, 0);
        }
    }
#pragma unroll
    for (int i = 0; i < 2; ++i) {
        int mbase = m0 + wr * 32 + i * 16 + lhi * 4;
#pragma unroll
        for (int j = 0; j < 4; ++j) {
            int n = wc * 64 + j * 16 + l15;
            float bv = b3[n];
#pragma unroll
            for (int q = 0; q < 4; ++q) {
                size_t off = (size_t)(mbase + q) * 128 + n;
                out[off] = acc[i][j][q] + x1[off] + bv;
            }
        }
    }
}

// ---- workspace layout (bytes) ----
constexpr size_t ALIGN_UP(size_t x) { return (x + 255) & ~(size_t)255; }
constexpr size_t SZ_X1   = ALIGN_UP((size_t)BN_ROWS * DIM_ * 4);       // f32
constexpr size_t SZ_RT   = ALIGN_UP((size_t)BN_ROWS * E_ * 4);         // f32
constexpr size_t SZ_A1   = ALIGN_UP((size_t)32 * 512 * 32 * 2);        // bf16
constexpr size_t SZ_A2   = ALIGN_UP((size_t)2 * 512 * 512 * 2);        // bf16
constexpr size_t SZ_XNT  = ALIGN_UP((size_t)B_ * 128 * 512 * 2);       // bf16
constexpr size_t SZ_YT   = ALIGN_UP((size_t)B_ * 128 * 1024 * 2);      // bf16
constexpr size_t SZ_XN2B = ALIGN_UP((size_t)BN_ROWS * DIM_ * 2);       // bf16
constexpr size_t SZ_H    = ALIGN_UP((size_t)BN_ROWS * HID_ * 2);       // bf16
constexpr size_t SZ_WT   = ALIGN_UP((size_t)128 * 512 * 2);            // bf16 (each)

extern "C" void kernel_launch(void* const* d_in, const int* in_sizes, int n_in,
                              void* d_out, int out_size, void* d_ws, size_t ws_size,
                              hipStream_t stream) {
    const float* x      = (const float*)d_in[0];
    const float* bias   = (const float*)d_in[1];
    const float* attn_s = (const float*)d_in[2];
    const float* ffn_s  = (const float*)d_in[3];
    const float* Wr     = (const float*)d_in[4];
    const float* br     = (const float*)d_in[5];
    const float* E1     = (const float*)d_in[6];
    const float* E2     = (const float*)d_in[7];
    const float* lq1    = (const float*)d_in[8];
    const float* lk1    = (const float*)d_in[9];
    const float* lq2    = (const float*)d_in[10];
    const float* lk2    = (const float*)d_in[11];
    // d_in[12] = outer_lambda: unused (outer mixing matrix == identity)
    const float* W1     = (const float*)d_in[13];
    const float* b1     = (const float*)d_in[14];
    const float* W2     = (const float*)d_in[15];
    const float* b2     = (const float*)d_in[16];
    const float* W3     = (const float*)d_in[17];
    const float* b3     = (const float*)d_in[18];

    char* p = (char*)d_ws;
    float* x1   = (float*)p;            p += SZ_X1;
    float* rt   = (float*)p;            p += SZ_RT;
    short* A1nb = (short*)p;            p += SZ_A1;
    short* A2nb = (short*)p;            p += SZ_A2;
    short* xnT  = (short*)p;            p += SZ_XNT;
    short* YT   = (short*)p;            p += SZ_YT;
    short* xn2b = (short*)p;            p += SZ_XN2B;
    short* h    = (short*)p;            p += SZ_H;
    short* W1T  = (short*)p;            p += SZ_WT;
    short* W2T  = (short*)p;            p += SZ_WT;
    short* W3T  = (short*)p;            p += SZ_WT;
    float* lam  = (float*)p;            p += 256;

    float* out_x   = (float*)d_out;
    float* out_idx = out_x + (size_t)BN_ROWS * DIM_;  // indices stored as float values

    float lam_init = 0.8f - 0.6f * expf(-0.3f);  // DEPTH = 1

    hipLaunchKernelGGL(k_misc, dim3(NMISC), dim3(256), 0, stream,
                       x, attn_s, Wr, br, bias, rt, out_idx, xnT,
                       E1, A1nb, E2, A2nb, W1, W2, W3, W1T, W2T, W3T,
                       lq1, lk1, lq2, lk2, lam_init, lam);
    hipLaunchKernelGGL(k_gemm_y, dim3(512), dim3(256), 0, stream, A2nb, xnT, YT);
    hipLaunchKernelGGL(k_attn, dim3(512), dim3(256), 0, stream, A1nb, rt, YT, x, lam, ffn_s, x1, xn2b);
    hipLaunchKernelGGL(k_ffn1, dim3(2048), dim3(256), 0, stream, xn2b, W1T, b1, W2T, b2, h);
    hipLaunchKernelGGL(k_ffn2, dim3(512), dim3(256), 0, stream, h, W3T, b3, x1, out_x);
}

// Round 8
// 197.140 us; speedup vs baseline: 1.0335x; 1.0335x over previous
//
#include <hip/hip_runtime.h>
#include <math.h>

#define B_ 64
#define N_ 512
#define DIM_ 128
#define E_ 16
#define G_ 32
#define TOPK_ 4
#define HID_ 512

constexpr int BN_ROWS = B_ * N_;  // 32768

using bf16x8 = __attribute__((ext_vector_type(8))) short;
using s16x4  = __attribute__((ext_vector_type(4))) short;
using f32x4  = __attribute__((ext_vector_type(4))) float;

__device__ __forceinline__ float bf2f(short s) {
    union { unsigned u; float f; } x;
    x.u = ((unsigned)(unsigned short)s) << 16;
    return x.f;
}
__device__ __forceinline__ short f2bf(float f) {
    union { float f; unsigned u; } x;
    x.f = f;
    unsigned r = x.u + 0x7FFF + ((x.u >> 16) & 1);  // RNE
    return (short)(r >> 16);
}

// read one MFMA fragment (8 bf16, 16B) from a [rows][64] bf16 LDS tile with XOR swizzle
__device__ __forceinline__ bf16x8 frag_ld(const short* base, int row, int ks, int lhi) {
    int addr = row * 128 + (((ks * 64) + lhi * 16) ^ ((row & 7) << 4));
    return *(const bf16x8*)((const char*)base + addr);
}
// same for a [rows][128] tile (row stride 256 B), ks in 0..3
__device__ __forceinline__ bf16x8 frag_ld128(const short* base, int row, int ks, int lhi) {
    int addr = row * 256 + (((ks * 64) + lhi * 16) ^ ((row & 7) << 4));
    return *(const bf16x8*)((const char*)base + addr);
}

// async global->LDS, 16B per lane; LDS dest = wave-uniform base + lane*16
typedef __attribute__((address_space(3))) void lds_vt;
typedef __attribute__((address_space(1))) const void gbl_vt;
__device__ __forceinline__ void gl2lds(const void* g, void* l) {
    __builtin_amdgcn_global_load_lds((gbl_vt*)g, (lds_vt*)l, 16, 0, 0);
}
#define WAIT_VMCNT(N) do { asm volatile("s_waitcnt vmcnt(" #N ")" ::: "memory"); \
    __builtin_amdgcn_sched_barrier(0); } while (0)
__device__ __forceinline__ void barrier_() {
    __builtin_amdgcn_sched_barrier(0);
    __builtin_amdgcn_s_barrier();
    __builtin_amdgcn_sched_barrier(0);
}
__device__ __forceinline__ void lgkm0_bar() {
    asm volatile("s_waitcnt lgkmcnt(0)" ::: "memory");
    __builtin_amdgcn_sched_barrier(0);
    __builtin_amdgcn_s_barrier();
    __builtin_amdgcn_sched_barrier(0);
}

// ================= k_misc: all preprocessing in ONE launch, grid-sectioned =================
constexpr int NPRE = BN_ROWS / 4;     // 8192: fused rmsnorm+route (4 rows/block)
constexpr int NXNT = B_ * 16;         // 1024: fused rmsnorm+transpose -> xnT bf16
constexpr int NSMG = 32 * 512 / 8;    // 2048: softmax over G
constexpr int NSMN = 1024 / 4;        // 256: softmax over N
constexpr int NTW  = 64 * 3;          // 192: weight transposes
constexpr int NMISC = NPRE + NXNT + NSMG + NSMN + NTW + 1;  // +1 lambda

__global__ __launch_bounds__(256) void k_misc(
    const float* __restrict__ x, const float* __restrict__ attn_s,
    const float* __restrict__ Wr, const float* __restrict__ br, const float* __restrict__ bias,
    float* __restrict__ route, float* __restrict__ topk_out,
    short* __restrict__ xnT,
    const float* __restrict__ E1, short* __restrict__ A1nb,
    const float* __restrict__ E2, short* __restrict__ A2nb,
    const float* __restrict__ W1, const float* __restrict__ W2, const float* __restrict__ W3,
    short* __restrict__ W1T, short* __restrict__ W2T, short* __restrict__ W3T,
    const float* __restrict__ lq1, const float* __restrict__ lk1,
    const float* __restrict__ lq2, const float* __restrict__ lk2,
    float lam_init, float* __restrict__ lam_out) {
    __shared__ float tb[32][129];
    __shared__ float invb[32];
    __shared__ float tw[32][33];
    int blk = blockIdx.x;
    int tid = threadIdx.x;

    if (blk < NPRE) {  // ---- fused rmsnorm + route (shfl GEMV + rank top-k): wave = one row ----
        int w = tid >> 6, lane = tid & 63;
        int row = blk * 4 + w;
        float2 v = ((const float2*)(x + (size_t)row * DIM_))[lane];
        float ss = v.x * v.x + v.y * v.y;
        for (int off = 32; off; off >>= 1) ss += __shfl_xor(ss, off);
        float inv = 1.0f / (sqrtf(ss * (1.0f / DIM_)) + 1e-8f);
        float2 s = ((const float2*)attn_s)[lane];
        float xn0 = v.x * inv * s.x;   // element d = 2*lane
        float xn1 = v.y * inv * s.y;   // element d = 2*lane+1
        int e = lane & 15, chunk = lane >> 4;
        float acc = 0.f;
#pragma unroll
        for (int j = 0; j < 16; ++j) {
            int srcl = chunk * 16 + j;
            float a0 = __shfl(xn0, srcl);
            float a1 = __shfl(xn1, srcl);
            int d0 = chunk * 32 + 2 * j;
            acc += a0 * Wr[d0 * E_ + e] + a1 * Wr[(d0 + 1) * E_ + e];
        }
        acc += __shfl_xor(acc, 16);
        acc += __shfl_xor(acc, 32);
        float gate = 1.0f / (1.0f + expf(-(acc + br[e])));
        float vv = gate + bias[0];
        int rank = 0;
#pragma unroll
        for (int i = 0; i < 16; ++i) {
            float vi = __shfl(vv, i);
            rank += ((vi > vv) || (vi == vv && i < e)) ? 1 : 0;
        }
        bool selq = (rank < TOPK_) && (lane < 16);
        float contrib = selq ? gate : 0.f;
        float ssum = contrib;
        ssum += __shfl_xor(ssum, 1); ssum += __shfl_xor(ssum, 2);
        ssum += __shfl_xor(ssum, 4); ssum += __shfl_xor(ssum, 8);
        if (lane < 16) route[(size_t)row * E_ + e] = selq ? gate / ssum : 0.0f;
        if (selq) topk_out[(size_t)row * TOPK_ + rank] = (float)e;
        return;
    }
    blk -= NPRE;

    if (blk < NXNT) {  // ---- fused rmsnorm + transpose: xnT[b][c][j] bf16 ----
        int b = blk >> 4, j0 = (blk & 15) * 32;
        const float* src = x + (size_t)(b * 512 + j0) * 128;
        int r = tid >> 3, c8 = tid & 7;
#pragma unroll
        for (int it = 0; it < 4; ++it) {
            int c4 = c8 + it * 8;
            float4 w4 = *(const float4*)(src + (size_t)r * 128 + c4 * 4);
            tb[r][c4 * 4 + 0] = w4.x; tb[r][c4 * 4 + 1] = w4.y;
            tb[r][c4 * 4 + 2] = w4.z; tb[r][c4 * 4 + 3] = w4.w;
        }
        __syncthreads();
        int sg = tid & 7;
        float ps = 0.f;
#pragma unroll
        for (int j = 0; j < 16; ++j) { float e2 = tb[r][sg * 16 + j]; ps += e2 * e2; }
        ps += __shfl_xor(ps, 1); ps += __shfl_xor(ps, 2); ps += __shfl_xor(ps, 4);
        if (sg == 0) invb[r] = 1.0f / (sqrtf(ps * (1.0f / DIM_)) + 1e-8f);
        __syncthreads();
        int c = tid >> 1, half = tid & 1;
        float sc = attn_s[c];
        short ov[16];
#pragma unroll
        for (int j = 0; j < 16; ++j) {
            int jj = half * 16 + j;
            ov[j] = f2bf(tb[jj][c] * invb[jj] * sc);
        }
        short* dst = xnT + (size_t)(b * 128 + c) * 512 + j0 + half * 16;
        *(bf16x8*)dst = *(bf16x8*)ov;
        *(bf16x8*)(dst + 8) = *(bf16x8*)(ov + 8);
        return;
    }
    blk -= NXNT;

    if (blk < NSMG) {  // ---- softmax over G=32 -> bf16 ----
        int row = blk * 8 + (tid >> 5);
        int l = tid & 31;
        float v = E1[(size_t)row * 32 + l];
        float m = v;
        for (int off = 16; off; off >>= 1) m = fmaxf(m, __shfl_xor(m, off));
        float ev = expf(v - m);
        float s = ev;
        for (int off = 16; off; off >>= 1) s += __shfl_xor(s, off);
        A1nb[(size_t)row * 32 + l] = f2bf(ev / s);
        return;
    }
    blk -= NSMG;

    if (blk < NSMN) {  // ---- softmax over N=512 -> bf16 ----
        int row = blk * 4 + (tid >> 6);
        int l = tid & 63;
        const float* p = E2 + (size_t)row * 512;
        float v[8];
        float m = -1e30f;
#pragma unroll
        for (int j = 0; j < 8; ++j) { v[j] = p[l + j * 64]; m = fmaxf(m, v[j]); }
        for (int off = 32; off; off >>= 1) m = fmaxf(m, __shfl_xor(m, off));
        float s = 0.f;
#pragma unroll
        for (int j = 0; j < 8; ++j) { v[j] = expf(v[j] - m); s += v[j]; }
        for (int off = 32; off; off >>= 1) s += __shfl_xor(s, off);
        float inv = 1.0f / s;
        short* q = A2nb + (size_t)row * 512;
#pragma unroll
        for (int j = 0; j < 8; ++j) q[l + j * 64] = f2bf(v[j] * inv);
        return;
    }
    blk -= NSMN;

    if (blk < NTW) {  // ---- weight transposes -> bf16 [C][R] ----
        int m = blk >> 6, tile = blk & 63;
        const float* S = (m == 0) ? W1 : (m == 1) ? W2 : W3;
        short* D = (m == 0) ? W1T : (m == 1) ? W2T : W3T;
        int R = (m == 2) ? 512 : 128, C = (m == 2) ? 128 : 512;
        int ctiles = C / 32;
        int r0 = (tile / ctiles) * 32, c0 = (tile % ctiles) * 32;
        int tx = tid & 31, ty = tid >> 5;
#pragma unroll
        for (int r = 0; r < 4; ++r) tw[ty * 4 + r][tx] = S[(size_t)(r0 + ty * 4 + r) * C + c0 + tx];
        __syncthreads();
#pragma unroll
        for (int r = 0; r < 4; ++r) D[(size_t)(c0 + ty * 4 + r) * R + r0 + tx] = f2bf(tw[tx][ty * 4 + r]);
        return;
    }

    // ---- lambda (1 block, wave 0) ----
    if (tid < 64) {
        int l = tid;
        float s1 = lq1[l] * lk1[l] + lq1[l + 64] * lk1[l + 64];
        float s2 = lq2[l] * lk2[l] + lq2[l + 64] * lk2[l + 64];
        for (int off = 32; off; off >>= 1) {
            s1 += __shfl_xor(s1, off);
            s2 += __shfl_xor(s2, off);
        }
        if (l == 0) lam_out[0] = -(expf(s1) - expf(s2) + lam_init);
    }
}

// ================= Y-GEMM (gload_lds dbuf + COUNTED vmcnt) =================
__global__ __launch_bounds__(256) void k_gemm_y(const short* __restrict__ A2nb,
                                                const short* __restrict__ xnT,
                                                short* __restrict__ YT) {
    alignas(16) __shared__ short As0[128 * 64];
    alignas(16) __shared__ short Bs0[128 * 64];
    alignas(16) __shared__ short As1[128 * 64];
    alignas(16) __shared__ short Bs1[128 * 64];
    int id = blockIdx.x;
    int nid = ((id & 7) << 6) + (id >> 3);   // XCD-chunked
    int m0 = (nid & 3) * 128;
    int be = nid >> 2, b = be >> 1, e = be & 1;
    int tid = threadIdx.x, lane = tid & 63, wid = tid >> 6;
    int l15 = lane & 15, lhi = lane >> 4;
    int wr = wid >> 1, wc = wid & 1;
    const short* Asrc = A2nb + (size_t)e * 512 * 512 + (size_t)m0 * 512;
    const short* Bsrc = xnT + (size_t)b * 128 * 512;
    int row8 = lane >> 3;
    int chunk8 = (lane & 7) ^ row8;  // pre-swizzled source chunk

    auto stage = [&](short* Ad, short* Bd, int k0) {
#pragma unroll
        for (int t = 0; t < 4; ++t) {
            int i = wid * 4 + t;
            int row = i * 8 + row8;
            gl2lds(Asrc + (size_t)row * 512 + k0 + chunk8 * 8, (char*)Ad + i * 1024);
            gl2lds(Bsrc + (size_t)row * 512 + k0 + chunk8 * 8, (char*)Bd + i * 1024);
        }
    };
    f32x4 acc[4][4] = {};
    stage(As0, Bs0, 0);
    for (int s = 0; s < 8; ++s) {
        const short* Ac = (s & 1) ? As1 : As0;
        const short* Bc = (s & 1) ? Bs1 : Bs0;
        if (s < 7) {
            stage((s & 1) ? As0 : As1, (s & 1) ? Bs0 : Bs1, (s + 1) * 64);
            WAIT_VMCNT(8);   // counted: only next's 8 remain in flight
        } else {
            WAIT_VMCNT(0);
        }
        barrier_();
#pragma unroll
        for (int ks = 0; ks < 2; ++ks) {
            bf16x8 af[4], bfr[4];
#pragma unroll
            for (int i = 0; i < 4; ++i) af[i] = frag_ld(Ac, wr * 64 + i * 16 + l15, ks, lhi);
#pragma unroll
            for (int j = 0; j < 4; ++j) bfr[j] = frag_ld(Bc, wc * 64 + j * 16 + l15, ks, lhi);
#pragma unroll
            for (int i = 0; i < 4; ++i)
#pragma unroll
                for (int j = 0; j < 4; ++j)
                    acc[i][j] = __builtin_amdgcn_mfma_f32_16x16x32_bf16(af[i], bfr[j], acc[i][j], 0, 0, 0);
        }
        barrier_();  // WAR guard before next stage overwrites
    }
    short* Yb = YT + (size_t)b * 128 * 1024 + e * 512;
#pragma unroll
    for (int i = 0; i < 4; ++i) {
        int mbase = m0 + wr * 64 + i * 16 + lhi * 4;
#pragma unroll
        for (int j = 0; j < 4; ++j) {
            int n = wc * 64 + j * 16 + l15;
            s16x4 o;
#pragma unroll
            for (int q = 0; q < 4; ++q) o[q] = f2bf(acc[i][j][q]);
            *(s16x4*)(Yb + (size_t)n * 1024 + mbase) = o;
        }
    }
}

// ================= attn (counted vmcnt, fused residual + FFN rmsnorm) =================
__global__ __launch_bounds__(256) void k_attn(const short* __restrict__ A1nb,
                                              const float* __restrict__ route,
                                              const short* __restrict__ YT,
                                              const float* __restrict__ x,
                                              const float* __restrict__ lam_p,
                                              const float* __restrict__ ffn_s,
                                              float* __restrict__ x1,
                                              short* __restrict__ xn2b) {
    alignas(16) __shared__ short Ab0[64 * 64];
    alignas(16) __shared__ short Ab1[64 * 64];
    alignas(16) __shared__ short Bb0[128 * 64];
    alignas(16) __shared__ short Bb1[128 * 64];
    __shared__ float ssbuf[2][64];
    int id = blockIdx.x;
    int nid = ((id & 7) << 6) + (id >> 3);
    int m0 = (nid & 7) * 64;
    int b = nid >> 3;
    float lam = lam_p[0];
    int tid = threadIdx.x, lane = tid & 63, wid = tid >> 6;
    int l15 = lane & 15, lhi = lane >> 4;
    int wr = wid >> 1, wc = wid & 1;
    const short* YTb = YT + (size_t)b * 128 * 1024;
    int row8 = lane >> 3;
    int chunk8 = (lane & 7) ^ row8;

    auto stageB = [&](short* Bd, int k0) {
#pragma unroll
        for (int t = 0; t < 4; ++t) {
            int i = wid * 4 + t;
            int row = i * 8 + row8;
            gl2lds(YTb + (size_t)row * 1024 + k0 + chunk8 * 8, (char*)Bd + i * 1024);
        }
    };
    auto loadA = [&](float (&rv)[2], bf16x8 (&ar)[2], int sn) {
#pragma unroll
        for (int r = 0; r < 2; ++r) {
            int idx = tid + r * 256, rowl = idx >> 3, slot = idx & 7;
            int t = sn * 2 + (slot >> 2);
            int gi = m0 + rowl;
            rv[r] = route[((size_t)b * 512 + gi) * 16 + (t & 15)] * (t >= 16 ? lam : 1.0f);
            ar[r] = *(const bf16x8*)(A1nb + ((size_t)t * 512 + gi) * 32 + (slot & 3) * 8);
        }
    };
    auto writeA = [&](short* dst, float (&rv)[2], bf16x8 (&ar)[2]) {
#pragma unroll
        for (int r = 0; r < 2; ++r) {
            int idx = tid + r * 256, rowl = idx >> 3, slot = idx & 7;
            bf16x8 o;
#pragma unroll
            for (int q = 0; q < 8; ++q) o[q] = f2bf(bf2f(ar[r][q]) * rv[r]);
            *(bf16x8*)((char*)dst + rowl * 128 + ((slot * 16) ^ ((rowl & 7) << 4))) = o;
        }
    };
    f32x4 acc[2][4] = {};
    auto compute = [&](const short* Ac, const short* Bc) {
#pragma unroll
        for (int ks = 0; ks < 2; ++ks) {
            bf16x8 af[2], bfr[4];
#pragma unroll
            for (int i = 0; i < 2; ++i) af[i] = frag_ld(Ac, wr * 32 + i * 16 + l15, ks, lhi);
#pragma unroll
            for (int j = 0; j < 4; ++j) bfr[j] = frag_ld(Bc, wc * 64 + j * 16 + l15, ks, lhi);
#pragma unroll
            for (int i = 0; i < 2; ++i)
#pragma unroll
                for (int j = 0; j < 4; ++j)
                    acc[i][j] = __builtin_amdgcn_mfma_f32_16x16x32_bf16(af[i], bfr[j], acc[i][j], 0, 0, 0);
        }
    };

    float rv0[2], rv1[2];
    bf16x8 ar0[2], ar1[2];
    stageB(Bb0, 0);
    loadA(rv0, ar0, 0);
    for (int sp = 0; sp < 8; ++sp) {
        int s = sp * 2;
        // even substep (cur = 0-set): prefetch odd set, counted wait
        stageB(Bb1, (s + 1) * 64);
        loadA(rv1, ar1, s + 1);
        WAIT_VMCNT(8);
        barrier_();
        writeA(Ab0, rv0, ar0);
        lgkm0_bar();
        compute(Ab0, Bb0);
        barrier_();
        // odd substep (cur = 1-set)
        if (s + 2 < 16) {
            stageB(Bb0, (s + 2) * 64);
            loadA(rv0, ar0, s + 2);
            WAIT_VMCNT(8);
        } else {
            WAIT_VMCNT(0);
        }
        barrier_();
        writeA(Ab1, rv1, ar1);
        lgkm0_bar();
        compute(Ab1, Bb1);
        barrier_();
    }
    // epilogue: residual, write x1, fused rmsnorm -> xn2b
    float x1v[2][4][4];
    float pss[2][4] = {};
#pragma unroll
    for (int i = 0; i < 2; ++i) {
        int gibase = m0 + wr * 32 + i * 16 + lhi * 4;
#pragma unroll
        for (int j = 0; j < 4; ++j) {
            int n = wc * 64 + j * 16 + l15;
#pragma unroll
            for (int q = 0; q < 4; ++q) {
                size_t off = ((size_t)b * 512 + gibase + q) * 128 + n;
                float val = acc[i][j][q] + x[off];
                x1[off] = val;
                x1v[i][j][q] = val;
                pss[i][q] += val * val;
            }
        }
    }
#pragma unroll
    for (int i = 0; i < 2; ++i)
#pragma unroll
        for (int q = 0; q < 4; ++q) {
            float p = pss[i][q];
            p += __shfl_xor(p, 1); p += __shfl_xor(p, 2);
            p += __shfl_xor(p, 4); p += __shfl_xor(p, 8);
            pss[i][q] = p;
        }
    if (l15 == 0) {
#pragma unroll
        for (int i = 0; i < 2; ++i)
#pragma unroll
            for (int q = 0; q < 4; ++q)
                ssbuf[wc][wr * 32 + i * 16 + lhi * 4 + q] = pss[i][q];
    }
    __syncthreads();
#pragma unroll
    for (int i = 0; i < 2; ++i)
#pragma unroll
        for (int q = 0; q < 4; ++q) {
            int rowl = wr * 32 + i * 16 + lhi * 4 + q;
            float ssum = ssbuf[0][rowl] + ssbuf[1][rowl];
            float inv = 1.0f / (sqrtf(ssum * (1.0f / DIM_)) + 1e-8f);
#pragma unroll
            for (int j = 0; j < 4; ++j) {
                int n = wc * 64 + j * 16 + l15;
                xn2b[((size_t)b * 512 + m0 + rowl) * 128 + n] = f2bf(x1v[i][j][q] * inv * ffn_s[n]);
            }
        }
}

// ================= FUSED FFN: out = x1 + SwiGLU(xn2b@W1,W2) @ W3 + b3 (h never leaves LDS) =================
// 512 blocks, 64 rows each. Per phase p (HID slice of 64): GEMM1 K=128 -> h-tile in LDS -> GEMM2 K=64 accum.
__global__ __launch_bounds__(256) void k_ffn(const short* __restrict__ xn2b,
                                             const short* __restrict__ W1T, const float* __restrict__ b1,
                                             const short* __restrict__ W2T, const float* __restrict__ b2,
                                             const short* __restrict__ W3T, const float* __restrict__ b3,
                                             const float* __restrict__ x1,
                                             float* __restrict__ out) {
    alignas(16) __shared__ short Xs[64 * 128];   // 16 KB [m][k] swz
    alignas(16) __shared__ short Hs[64 * 64];    //  8 KB [m][n] swz
    alignas(16) __shared__ short W1s[64 * 128];  // 16 KB [n][k] swz
    alignas(16) __shared__ short W2s[64 * 128];  // 16 KB
    alignas(16) __shared__ short W3s[128 * 64];  // 16 KB [c][n] swz
    int id = blockIdx.x;
    int nid = ((id & 7) << 6) + (id >> 3);   // XCD-chunked
    int m0 = nid * 64;
    int tid = threadIdx.x, lane = tid & 63, wid = tid >> 6;
    int l15 = lane & 15, lhi = lane >> 4;
    int wr = wid >> 1, wc = wid & 1;

    // staging lane mappings
    int r4 = lane >> 4;            // 4 rows per 1024B for 256B rows
    int c16 = lane & 15;
    int r8 = lane >> 3;            // 8 rows per 1024B for 128B rows
    int c8 = lane & 7;

    auto stageX = [&]() {  // [64][128] from xn2b rows m0..; once
#pragma unroll
        for (int t = 0; t < 4; ++t) {
            int i = wid * 4 + t;
            int row = i * 4 + r4;
            int cs = c16 ^ (row & 7);
            gl2lds(xn2b + (size_t)(m0 + row) * 128 + cs * 8, (char*)Xs + i * 1024);
        }
    };
    auto stageW12 = [&](int p) {  // W1s,W2s: [64][128] each, rows p*64..
        int n0 = p * 64;
#pragma unroll
        for (int t = 0; t < 8; ++t) {
            int i = wid * 8 + t;           // 0..31
            int which = i >> 4;            // 0: W1, 1: W2
            int ii = i & 15;
            int row = ii * 4 + r4;
            int cs = c16 ^ (row & 7);
            const short* S = which ? W2T : W1T;
            short* D = which ? (short*)W2s : (short*)W1s;
            gl2lds(S + (size_t)(n0 + row) * 128 + cs * 8, (char*)D + ii * 1024);
        }
    };
    auto stageW3 = [&](int p) {  // W3s: [128][64] from W3T[c][p*64..]
        int n0 = p * 64;
#pragma unroll
        for (int t = 0; t < 4; ++t) {
            int i = wid * 4 + t;           // 0..15
            int row = i * 8 + r8;
            int cs = c8 ^ (row & 7);
            gl2lds(W3T + (size_t)row * 512 + n0 + cs * 8, (char*)W3s + i * 1024);
        }
    };

    f32x4 aout[2][4] = {};
    stageX();
    stageW12(0);
    stageW3(0);
    WAIT_VMCNT(0);
    barrier_();
    for (int p = 0; p < 8; ++p) {
        // ---- GEMM1: h = silu(X@W1+b1)*(X@W2+b2), this 64-col slice ----
        f32x4 a1[2][2] = {}, a2[2][2] = {};
#pragma unroll
        for (int ks = 0; ks < 4; ++ks) {
            bf16x8 af[2], b1f[2], b2f[2];
#pragma unroll
            for (int i = 0; i < 2; ++i) af[i] = frag_ld128(Xs, wr * 32 + i * 16 + l15, ks, lhi);
#pragma unroll
            for (int j = 0; j < 2; ++j) {
                b1f[j] = frag_ld128(W1s, wc * 32 + j * 16 + l15, ks, lhi);
                b2f[j] = frag_ld128(W2s, wc * 32 + j * 16 + l15, ks, lhi);
            }
#pragma unroll
            for (int i = 0; i < 2; ++i)
#pragma unroll
                for (int j = 0; j < 2; ++j) {
                    a1[i][j] = __builtin_amdgcn_mfma_f32_16x16x32_bf16(af[i], b1f[j], a1[i][j], 0, 0, 0);
                    a2[i][j] = __builtin_amdgcn_mfma_f32_16x16x32_bf16(af[i], b2f[j], a2[i][j], 0, 0, 0);
                }
        }
        // ---- SwiGLU -> Hs (swizzled scalar writes) ----
        int nn0 = p * 64;
#pragma unroll
        for (int i = 0; i < 2; ++i) {
            int mloc = wr * 32 + i * 16 + lhi * 4;
#pragma unroll
            for (int j = 0; j < 2; ++j) {
                int nloc = wc * 32 + j * 16 + l15;
                float bb1 = b1[nn0 + nloc], bb2 = b2[nn0 + nloc];
#pragma unroll
                for (int q = 0; q < 4; ++q) {
                    float u = a1[i][j][q] + bb1;
                    float w2v = a2[i][j][q] + bb2;
                    float hv = u / (1.0f + expf(-u)) * w2v;
                    int mq = mloc + q;
                    *(short*)((char*)Hs + mq * 128 + ((nloc * 2) ^ ((mq & 7) << 4))) = f2bf(hv);
                }
            }
        }
        lgkm0_bar();                 // h visible to all; also: all waves done reading W1s/W2s
        if (p < 7) stageW12(p + 1);  // prefetch under GEMM2
        // ---- GEMM2: aout += h @ W3 slice ----
#pragma unroll
        for (int ks = 0; ks < 2; ++ks) {
            bf16x8 af[2], bfr[4];
#pragma unroll
            for (int i = 0; i < 2; ++i) af[i] = frag_ld(Hs, wr * 32 + i * 16 + l15, ks, lhi);
#pragma unroll
            for (int j = 0; j < 4; ++j) bfr[j] = frag_ld(W3s, wc * 64 + j * 16 + l15, ks, lhi);
#pragma unroll
            for (int i = 0; i < 2; ++i)
#pragma unroll
                for (int j = 0; j < 4; ++j)
                    aout[i][j] = __builtin_amdgcn_mfma_f32_16x16x32_bf16(af[i], bfr[j], aout[i][j], 0, 0, 0);
        }
        barrier_();                  // all done reading W3s/Hs
        if (p < 7) {
            stageW3(p + 1);
            WAIT_VMCNT(0);           // drain W12 (landed under GEMM2) + W3
            barrier_();
        }
    }
    // ---- epilogue: out = aout + x1 + b3 ----
#pragma unroll
    for (int i = 0; i < 2; ++i) {
        int mbase = m0 + wr * 32 + i * 16 + lhi * 4;
#pragma unroll
        for (int j = 0; j < 4; ++j) {
            int n = wc * 64 + j * 16 + l15;
            float bv = b3[n];
#pragma unroll
            for (int q = 0; q < 4; ++q) {
                size_t off = (size_t)(mbase + q) * 128 + n;
                out[off] = aout[i][j][q] + x1[off] + bv;
            }
        }
    }
}

// ---- workspace layout (bytes) ----
constexpr size_t ALIGN_UP(size_t x) { return (x + 255) & ~(size_t)255; }
constexpr size_t SZ_X1   = ALIGN_UP((size_t)BN_ROWS * DIM_ * 4);       // f32
constexpr size_t SZ_RT   = ALIGN_UP((size_t)BN_ROWS * E_ * 4);         // f32
constexpr size_t SZ_A1   = ALIGN_UP((size_t)32 * 512 * 32 * 2);        // bf16
constexpr size_t SZ_A2   = ALIGN_UP((size_t)2 * 512 * 512 * 2);        // bf16
constexpr size_t SZ_XNT  = ALIGN_UP((size_t)B_ * 128 * 512 * 2);       // bf16
constexpr size_t SZ_YT   = ALIGN_UP((size_t)B_ * 128 * 1024 * 2);      // bf16
constexpr size_t SZ_XN2B = ALIGN_UP((size_t)BN_ROWS * DIM_ * 2);       // bf16
constexpr size_t SZ_WT   = ALIGN_UP((size_t)128 * 512 * 2);            // bf16 (each)

extern "C" void kernel_launch(void* const* d_in, const int* in_sizes, int n_in,
                              void* d_out, int out_size, void* d_ws, size_t ws_size,
                              hipStream_t stream) {
    const float* x      = (const float*)d_in[0];
    const float* bias   = (const float*)d_in[1];
    const float* attn_s = (const float*)d_in[2];
    const float* ffn_s  = (const float*)d_in[3];
    const float* Wr     = (const float*)d_in[4];
    const float* br     = (const float*)d_in[5];
    const float* E1     = (const float*)d_in[6];
    const float* E2     = (const float*)d_in[7];
    const float* lq1    = (const float*)d_in[8];
    const float* lk1    = (const float*)d_in[9];
    const float* lq2    = (const float*)d_in[10];
    const float* lk2    = (const float*)d_in[11];
    // d_in[12] = outer_lambda: unused (outer mixing matrix == identity)
    const float* W1     = (const float*)d_in[13];
    const float* b1     = (const float*)d_in[14];
    const float* W2     = (const float*)d_in[15];
    const float* b2     = (const float*)d_in[16];
    const float* W3     = (const float*)d_in[17];
    const float* b3     = (const float*)d_in[18];

    char* p = (char*)d_ws;
    float* x1   = (float*)p;            p += SZ_X1;
    float* rt   = (float*)p;            p += SZ_RT;
    short* A1nb = (short*)p;            p += SZ_A1;
    short* A2nb = (short*)p;            p += SZ_A2;
    short* xnT  = (short*)p;            p += SZ_XNT;
    short* YT   = (short*)p;            p += SZ_YT;
    short* xn2b = (short*)p;            p += SZ_XN2B;
    short* W1T  = (short*)p;            p += SZ_WT;
    short* W2T  = (short*)p;            p += SZ_WT;
    short* W3T  = (short*)p;            p += SZ_WT;
    float* lam  = (float*)p;            p += 256;

    float* out_x   = (float*)d_out;
    float* out_idx = out_x + (size_t)BN_ROWS * DIM_;  // indices stored as float values

    float lam_init = 0.8f - 0.6f * expf(-0.3f);  // DEPTH = 1

    hipLaunchKernelGGL(k_misc, dim3(NMISC), dim3(256), 0, stream,
                       x, attn_s, Wr, br, bias, rt, out_idx, xnT,
                       E1, A1nb, E2, A2nb, W1, W2, W3, W1T, W2T, W3T,
                       lq1, lk1, lq2, lk2, lam_init, lam);
    hipLaunchKernelGGL(k_gemm_y, dim3(512), dim3(256), 0, stream, A2nb, xnT, YT);
    hipLaunchKernelGGL(k_attn, dim3(512), dim3(256), 0, stream, A1nb, rt, YT, x, lam, ffn_s, x1, xn2b);
    hipLaunchKernelGGL(k_ffn, dim3(512), dim3(256), 0, stream, xn2b, W1T, b1, W2T, b2, W3T, b3, x1, out_x);
}

// Round 9
// 183.217 us; speedup vs baseline: 1.1120x; 1.0760x over previous
//
#include <hip/hip_runtime.h>
#include <math.h>

#define B_ 64
#define N_ 512
#define DIM_ 128
#define E_ 16
#define G_ 32
#define TOPK_ 4
#define HID_ 512

constexpr int BN_ROWS = B_ * N_;  // 32768

using bf16x8 = __attribute__((ext_vector_type(8))) short;
using s16x4  = __attribute__((ext_vector_type(4))) short;
using f32x4  = __attribute__((ext_vector_type(4))) float;

__device__ __forceinline__ float bf2f(short s) {
    union { unsigned u; float f; } x;
    x.u = ((unsigned)(unsigned short)s) << 16;
    return x.f;
}
__device__ __forceinline__ short f2bf(float f) {
    union { float f; unsigned u; } x;
    x.f = f;
    unsigned r = x.u + 0x7FFF + ((x.u >> 16) & 1);  // RNE
    return (short)(r >> 16);
}

// read one MFMA fragment (8 bf16, 16B) from a [rows][64] bf16 LDS tile with XOR swizzle
__device__ __forceinline__ bf16x8 frag_ld(const short* base, int row, int ks, int lhi) {
    int addr = row * 128 + (((ks * 64) + lhi * 16) ^ ((row & 7) << 4));
    return *(const bf16x8*)((const char*)base + addr);
}
// same for a [rows][128] tile (row stride 256 B), ks in 0..3
__device__ __forceinline__ bf16x8 frag_ld128(const short* base, int row, int ks, int lhi) {
    int addr = row * 256 + (((ks * 64) + lhi * 16) ^ ((row & 7) << 4));
    return *(const bf16x8*)((const char*)base + addr);
}

// async global->LDS, 16B per lane; LDS dest = wave-uniform base + lane*16
typedef __attribute__((address_space(3))) void lds_vt;
typedef __attribute__((address_space(1))) const void gbl_vt;
__device__ __forceinline__ void gl2lds(const void* g, void* l) {
    __builtin_amdgcn_global_load_lds((gbl_vt*)g, (lds_vt*)l, 16, 0, 0);
}
#define WAIT_VMCNT(N) do { asm volatile("s_waitcnt vmcnt(" #N ")" ::: "memory"); \
    __builtin_amdgcn_sched_barrier(0); } while (0)
__device__ __forceinline__ void barrier_() {
    __builtin_amdgcn_sched_barrier(0);
    __builtin_amdgcn_s_barrier();
    __builtin_amdgcn_sched_barrier(0);
}
__device__ __forceinline__ void lgkm0_bar() {
    asm volatile("s_waitcnt lgkmcnt(0)" ::: "memory");
    __builtin_amdgcn_sched_barrier(0);
    __builtin_amdgcn_s_barrier();
    __builtin_amdgcn_sched_barrier(0);
}

// ================= k_misc: preprocessing, grid-sectioned =================
constexpr int NXNT = B_ * 16;         // 1024: fused rmsnorm + transpose + ROUTE (32 rows/block)
constexpr int NSMG = 32 * 512 / 8;    // 2048: softmax over G
constexpr int NSMN = 1024 / 4;        // 256: softmax over N
constexpr int NTW  = 64 * 3;          // 192: weight transposes
constexpr int NMISC = NXNT + NSMG + NSMN + NTW + 1;  // +1 lambda

__global__ __launch_bounds__(256) void k_misc(
    const float* __restrict__ x, const float* __restrict__ attn_s,
    const float* __restrict__ Wr, const float* __restrict__ br, const float* __restrict__ bias,
    float* __restrict__ route, float* __restrict__ topk_out,
    short* __restrict__ xnT,
    const float* __restrict__ E1, short* __restrict__ A1nb,
    const float* __restrict__ E2, short* __restrict__ A2nb,
    const float* __restrict__ W1, const float* __restrict__ W2, const float* __restrict__ W3,
    short* __restrict__ W1T, short* __restrict__ W2T, short* __restrict__ W3T,
    const float* __restrict__ lq1, const float* __restrict__ lk1,
    const float* __restrict__ lq2, const float* __restrict__ lk2,
    float lam_init, float* __restrict__ lam_out) {
    __shared__ float tb[32][132];   // 132: 16B-aligned rows for float4 reads
    __shared__ float invb[32];
    __shared__ float gbuf[32][17];
    __shared__ float tw[32][33];
    int blk = blockIdx.x;
    int tid = threadIdx.x;

    if (blk < NXNT) {  // ---- fused rmsnorm + transpose + route ----
        int b = blk >> 4, j0 = (blk & 15) * 32;
        const float* src = x + (size_t)(b * 512 + j0) * 128;
        int r = tid >> 3, c8 = tid & 7;
#pragma unroll
        for (int it = 0; it < 4; ++it) {
            int c4 = c8 + it * 8;
            float4 w4 = *(const float4*)(src + (size_t)r * 128 + c4 * 4);
            tb[r][c4 * 4 + 0] = w4.x; tb[r][c4 * 4 + 1] = w4.y;
            tb[r][c4 * 4 + 2] = w4.z; tb[r][c4 * 4 + 3] = w4.w;
        }
        __syncthreads();
        int sg = tid & 7;
        float ps = 0.f;
#pragma unroll
        for (int j = 0; j < 16; ++j) { float e2 = tb[r][sg * 16 + j]; ps += e2 * e2; }
        ps += __shfl_xor(ps, 1); ps += __shfl_xor(ps, 2); ps += __shfl_xor(ps, 4);
        if (sg == 0) invb[r] = 1.0f / (sqrtf(ps * (1.0f / DIM_)) + 1e-8f);
        __syncthreads();
        // -- route: 8 threads/row, 2 experts each (eb, eb+8) --
        {
            int eb = tid & 7;
            float invr = invb[r];
            float g0 = 0.f, g1 = 0.f;
#pragma unroll 4
            for (int d4 = 0; d4 < 32; ++d4) {
                float4 tv = *(const float4*)&tb[r][d4 * 4];
                float4 sv = *(const float4*)(attn_s + d4 * 4);
                float x0 = tv.x * sv.x, x1v = tv.y * sv.y, x2 = tv.z * sv.z, x3 = tv.w * sv.w;
                int d0 = d4 * 4;
                g0 += x0 * Wr[(d0 + 0) * 16 + eb] + x1v * Wr[(d0 + 1) * 16 + eb]
                    + x2 * Wr[(d0 + 2) * 16 + eb] + x3 * Wr[(d0 + 3) * 16 + eb];
                g1 += x0 * Wr[(d0 + 0) * 16 + eb + 8] + x1v * Wr[(d0 + 1) * 16 + eb + 8]
                    + x2 * Wr[(d0 + 2) * 16 + eb + 8] + x3 * Wr[(d0 + 3) * 16 + eb + 8];
            }
            float gate0 = 1.0f / (1.0f + expf(-(g0 * invr + br[eb])));
            float gate1 = 1.0f / (1.0f + expf(-(g1 * invr + br[eb + 8])));
            gbuf[r][eb] = gate0;
            gbuf[r][eb + 8] = gate1;
        }
        __syncthreads();
        {
            int eb = tid & 7;
            float bv = bias[0];
            float gate0 = gbuf[r][eb], gate1 = gbuf[r][eb + 8];
            float v0 = gate0 + bv, v1 = gate1 + bv;
            int rank0 = 0, rank1 = 0;
#pragma unroll
            for (int i = 0; i < 16; ++i) {
                float vi = gbuf[r][i] + bv;
                rank0 += ((vi > v0) || (vi == v0 && i < eb)) ? 1 : 0;
                rank1 += ((vi > v1) || (vi == v1 && i < eb + 8)) ? 1 : 0;
            }
            bool s0 = rank0 < TOPK_, s1 = rank1 < TOPK_;
            float s = (s0 ? gate0 : 0.f) + (s1 ? gate1 : 0.f);
            s += __shfl_xor(s, 1); s += __shfl_xor(s, 2); s += __shfl_xor(s, 4);
            size_t grow = (size_t)b * 512 + j0 + r;
            route[grow * 16 + eb]     = s0 ? gate0 / s : 0.f;
            route[grow * 16 + eb + 8] = s1 ? gate1 / s : 0.f;
            if (s0) topk_out[grow * 4 + rank0] = (float)eb;
            if (s1) topk_out[grow * 4 + rank1] = (float)(eb + 8);
        }
        // -- transpose -> xnT bf16 --
        int c = tid >> 1, half = tid & 1;
        float sc = attn_s[c];
        short ov[16];
#pragma unroll
        for (int j = 0; j < 16; ++j) {
            int jj = half * 16 + j;
            ov[j] = f2bf(tb[jj][c] * invb[jj] * sc);
        }
        short* dst = xnT + (size_t)(b * 128 + c) * 512 + j0 + half * 16;
        *(bf16x8*)dst = *(bf16x8*)ov;
        *(bf16x8*)(dst + 8) = *(bf16x8*)(ov + 8);
        return;
    }
    blk -= NXNT;

    if (blk < NSMG) {  // ---- softmax over G=32 -> bf16 ----
        int row = blk * 8 + (tid >> 5);
        int l = tid & 31;
        float v = E1[(size_t)row * 32 + l];
        float m = v;
        for (int off = 16; off; off >>= 1) m = fmaxf(m, __shfl_xor(m, off));
        float ev = expf(v - m);
        float s = ev;
        for (int off = 16; off; off >>= 1) s += __shfl_xor(s, off);
        A1nb[(size_t)row * 32 + l] = f2bf(ev / s);
        return;
    }
    blk -= NSMG;

    if (blk < NSMN) {  // ---- softmax over N=512 -> bf16 ----
        int row = blk * 4 + (tid >> 6);
        int l = tid & 63;
        const float* p = E2 + (size_t)row * 512;
        float v[8];
        float m = -1e30f;
#pragma unroll
        for (int j = 0; j < 8; ++j) { v[j] = p[l + j * 64]; m = fmaxf(m, v[j]); }
        for (int off = 32; off; off >>= 1) m = fmaxf(m, __shfl_xor(m, off));
        float s = 0.f;
#pragma unroll
        for (int j = 0; j < 8; ++j) { v[j] = expf(v[j] - m); s += v[j]; }
        for (int off = 32; off; off >>= 1) s += __shfl_xor(s, off);
        float inv = 1.0f / s;
        short* q = A2nb + (size_t)row * 512;
#pragma unroll
        for (int j = 0; j < 8; ++j) q[l + j * 64] = f2bf(v[j] * inv);
        return;
    }
    blk -= NSMN;

    if (blk < NTW) {  // ---- weight transposes -> bf16 [C][R] ----
        int m = blk >> 6, tile = blk & 63;
        const float* S = (m == 0) ? W1 : (m == 1) ? W2 : W3;
        short* D = (m == 0) ? W1T : (m == 1) ? W2T : W3T;
        int R = (m == 2) ? 512 : 128, C = (m == 2) ? 128 : 512;
        int ctiles = C / 32;
        int r0 = (tile / ctiles) * 32, c0 = (tile % ctiles) * 32;
        int tx = tid & 31, ty = tid >> 5;
#pragma unroll
        for (int r = 0; r < 4; ++r) tw[ty * 4 + r][tx] = S[(size_t)(r0 + ty * 4 + r) * C + c0 + tx];
        __syncthreads();
#pragma unroll
        for (int r = 0; r < 4; ++r) D[(size_t)(c0 + ty * 4 + r) * R + r0 + tx] = f2bf(tw[tx][ty * 4 + r]);
        return;
    }

    // ---- lambda (1 block, wave 0) ----
    if (tid < 64) {
        int l = tid;
        float s1 = lq1[l] * lk1[l] + lq1[l + 64] * lk1[l + 64];
        float s2 = lq2[l] * lk2[l] + lq2[l + 64] * lk2[l + 64];
        for (int off = 32; off; off >>= 1) {
            s1 += __shfl_xor(s1, off);
            s2 += __shfl_xor(s2, off);
        }
        if (l == 0) lam_out[0] = -(expf(s1) - expf(s2) + lam_init);
    }
}

// ================= Y-GEMM (gload_lds dbuf + counted vmcnt) =================
__global__ __launch_bounds__(256) void k_gemm_y(const short* __restrict__ A2nb,
                                                const short* __restrict__ xnT,
                                                short* __restrict__ YT) {
    alignas(16) __shared__ short As0[128 * 64];
    alignas(16) __shared__ short Bs0[128 * 64];
    alignas(16) __shared__ short As1[128 * 64];
    alignas(16) __shared__ short Bs1[128 * 64];
    int id = blockIdx.x;
    int nid = ((id & 7) << 6) + (id >> 3);   // XCD-chunked
    int m0 = (nid & 3) * 128;
    int be = nid >> 2, b = be >> 1, e = be & 1;
    int tid = threadIdx.x, lane = tid & 63, wid = tid >> 6;
    int l15 = lane & 15, lhi = lane >> 4;
    int wr = wid >> 1, wc = wid & 1;
    const short* Asrc = A2nb + (size_t)e * 512 * 512 + (size_t)m0 * 512;
    const short* Bsrc = xnT + (size_t)b * 128 * 512;
    int row8 = lane >> 3;
    int chunk8 = (lane & 7) ^ row8;  // pre-swizzled source chunk

    auto stage = [&](short* Ad, short* Bd, int k0) {
#pragma unroll
        for (int t = 0; t < 4; ++t) {
            int i = wid * 4 + t;
            int row = i * 8 + row8;
            gl2lds(Asrc + (size_t)row * 512 + k0 + chunk8 * 8, (char*)Ad + i * 1024);
            gl2lds(Bsrc + (size_t)row * 512 + k0 + chunk8 * 8, (char*)Bd + i * 1024);
        }
    };
    f32x4 acc[4][4] = {};
    stage(As0, Bs0, 0);
    for (int s = 0; s < 8; ++s) {
        const short* Ac = (s & 1) ? As1 : As0;
        const short* Bc = (s & 1) ? Bs1 : Bs0;
        if (s < 7) {
            stage((s & 1) ? As0 : As1, (s & 1) ? Bs0 : Bs1, (s + 1) * 64);
            WAIT_VMCNT(8);
        } else {
            WAIT_VMCNT(0);
        }
        barrier_();
#pragma unroll
        for (int ks = 0; ks < 2; ++ks) {
            bf16x8 af[4], bfr[4];
#pragma unroll
            for (int i = 0; i < 4; ++i) af[i] = frag_ld(Ac, wr * 64 + i * 16 + l15, ks, lhi);
#pragma unroll
            for (int j = 0; j < 4; ++j) bfr[j] = frag_ld(Bc, wc * 64 + j * 16 + l15, ks, lhi);
#pragma unroll
            for (int i = 0; i < 4; ++i)
#pragma unroll
                for (int j = 0; j < 4; ++j)
                    acc[i][j] = __builtin_amdgcn_mfma_f32_16x16x32_bf16(af[i], bfr[j], acc[i][j], 0, 0, 0);
        }
        barrier_();
    }
    short* Yb = YT + (size_t)b * 128 * 1024 + e * 512;
#pragma unroll
    for (int i = 0; i < 4; ++i) {
        int mbase = m0 + wr * 64 + i * 16 + lhi * 4;
#pragma unroll
        for (int j = 0; j < 4; ++j) {
            int n = wc * 64 + j * 16 + l15;
            s16x4 o;
#pragma unroll
            for (int q = 0; q < 4; ++q) o[q] = f2bf(acc[i][j][q]);
            *(s16x4*)(Yb + (size_t)n * 1024 + mbase) = o;
        }
    }
}

// ================= FUSED attn + FFN: out = x1 + SwiGLU(rms(x1)@W1,W2)@W3 + b3, x1 = x + attn =================
// x1 lives in registers; rms(x1)*ffn_scale goes straight into LDS (Xs). No x1/xn2b HBM traffic.
__global__ __launch_bounds__(256) void k_attn_ffn(
    const short* __restrict__ A1nb, const float* __restrict__ route,
    const short* __restrict__ YT, const float* __restrict__ x,
    const float* __restrict__ lam_p, const float* __restrict__ ffn_s,
    const short* __restrict__ W1T, const float* __restrict__ b1,
    const short* __restrict__ W2T, const float* __restrict__ b2,
    const short* __restrict__ W3T, const float* __restrict__ b3,
    float* __restrict__ out) {
    alignas(16) __shared__ char L[73728];      // 72 KB -> 2 blocks/CU
    short* Xs    = (short*)L;                  // [64][128] swz, 16K (FFN A operand)
    short* Hs    = (short*)(L + 16384);        // [64][64] swz, 8K (FFN h tile)
    float* ssbuf = (float*)(L + 16384);        // 512 B, epilogue only (before Hs used)
    short* W1s   = (short*)(L + 24576);        // 16K
    short* W2s   = (short*)(L + 40960);        // 16K
    short* W3s   = (short*)(L + 57344);        // 16K
    // attn-phase aliases (dead before any W staging):
    short* Ab0 = (short*)(L + 16384);
    short* Ab1 = (short*)(L + 24576);
    short* Bb0 = (short*)(L + 32768);
    short* Bb1 = (short*)(L + 49152);

    int id = blockIdx.x;
    int nid = ((id & 7) << 6) + (id >> 3);   // XCD-chunked; blocks sharing b on one XCD
    int m0 = (nid & 7) * 64;
    int b = nid >> 3;
    float lam = lam_p[0];
    int tid = threadIdx.x, lane = tid & 63, wid = tid >> 6;
    int l15 = lane & 15, lhi = lane >> 4;
    int wr = wid >> 1, wc = wid & 1;
    const short* YTb = YT + (size_t)b * 128 * 1024;
    int row8 = lane >> 3;
    int chunk8 = (lane & 7) ^ row8;
    int r4 = lane >> 4, c16 = lane & 15;

    // ---------- attn phase ----------
    auto stageB = [&](short* Bd, int k0) {
#pragma unroll
        for (int t = 0; t < 4; ++t) {
            int i = wid * 4 + t;
            int row = i * 8 + row8;
            gl2lds(YTb + (size_t)row * 1024 + k0 + chunk8 * 8, (char*)Bd + i * 1024);
        }
    };
    auto loadA = [&](float (&rv)[2], bf16x8 (&ar)[2], int sn) {
#pragma unroll
        for (int r = 0; r < 2; ++r) {
            int idx = tid + r * 256, rowl = idx >> 3, slot = idx & 7;
            int t = sn * 2 + (slot >> 2);
            int gi = m0 + rowl;
            rv[r] = route[((size_t)b * 512 + gi) * 16 + (t & 15)] * (t >= 16 ? lam : 1.0f);
            ar[r] = *(const bf16x8*)(A1nb + ((size_t)t * 512 + gi) * 32 + (slot & 3) * 8);
        }
    };
    auto writeA = [&](short* dst, float (&rv)[2], bf16x8 (&ar)[2]) {
#pragma unroll
        for (int r = 0; r < 2; ++r) {
            int idx = tid + r * 256, rowl = idx >> 3, slot = idx & 7;
            bf16x8 o;
#pragma unroll
            for (int q = 0; q < 8; ++q) o[q] = f2bf(bf2f(ar[r][q]) * rv[r]);
            *(bf16x8*)((char*)dst + rowl * 128 + ((slot * 16) ^ ((rowl & 7) << 4))) = o;
        }
    };
    f32x4 acc[2][4] = {};
    auto compute = [&](const short* Ac, const short* Bc) {
#pragma unroll
        for (int ks = 0; ks < 2; ++ks) {
            bf16x8 af[2], bfr[4];
#pragma unroll
            for (int i = 0; i < 2; ++i) af[i] = frag_ld(Ac, wr * 32 + i * 16 + l15, ks, lhi);
#pragma unroll
            for (int j = 0; j < 4; ++j) bfr[j] = frag_ld(Bc, wc * 64 + j * 16 + l15, ks, lhi);
#pragma unroll
            for (int i = 0; i < 2; ++i)
#pragma unroll
                for (int j = 0; j < 4; ++j)
                    acc[i][j] = __builtin_amdgcn_mfma_f32_16x16x32_bf16(af[i], bfr[j], acc[i][j], 0, 0, 0);
        }
    };

    float rv0[2], rv1[2];
    bf16x8 ar0[2], ar1[2];
    stageB(Bb0, 0);
    loadA(rv0, ar0, 0);
    for (int sp = 0; sp < 8; ++sp) {
        int s = sp * 2;
        stageB(Bb1, (s + 1) * 64);
        loadA(rv1, ar1, s + 1);
        WAIT_VMCNT(8);
        barrier_();
        writeA(Ab0, rv0, ar0);
        lgkm0_bar();
        compute(Ab0, Bb0);
        barrier_();
        if (s + 2 < 16) {
            stageB(Bb0, (s + 2) * 64);
            loadA(rv0, ar0, s + 2);
            WAIT_VMCNT(8);
        } else {
            WAIT_VMCNT(0);
        }
        barrier_();
        writeA(Ab1, rv1, ar1);
        lgkm0_bar();
        compute(Ab1, Bb1);
        barrier_();
    }

    // ---------- W staging (issued early; lands under epilogue) ----------
    auto stageW12 = [&](int p) {
        int n0 = p * 64;
#pragma unroll
        for (int t = 0; t < 8; ++t) {
            int i = wid * 8 + t;
            int which = i >> 4, ii = i & 15;
            int row = ii * 4 + r4;
            int cs = c16 ^ (row & 7);
            const short* S = which ? W2T : W1T;
            short* D = which ? (short*)W2s : (short*)W1s;
            gl2lds(S + (size_t)(n0 + row) * 128 + cs * 8, (char*)D + ii * 1024);
        }
    };
    auto stageW3 = [&](int p) {
        int n0 = p * 64;
#pragma unroll
        for (int t = 0; t < 4; ++t) {
            int i = wid * 4 + t;
            int row = i * 8 + row8;
            int cs = (lane & 7) ^ (row & 7);
            gl2lds(W3T + (size_t)row * 512 + n0 + cs * 8, (char*)W3s + i * 1024);
        }
    };
    stageW12(0);
    stageW3(0);

    // ---------- epilogue: x1 (registers) + rmsnorm -> Xs ----------
    float x1v[2][4][4];
    float pss[2][4] = {};
#pragma unroll
    for (int i = 0; i < 2; ++i) {
        int gibase = m0 + wr * 32 + i * 16 + lhi * 4;
#pragma unroll
        for (int j = 0; j < 4; ++j) {
            int n = wc * 64 + j * 16 + l15;
#pragma unroll
            for (int q = 0; q < 4; ++q) {
                size_t off = ((size_t)b * 512 + gibase + q) * 128 + n;
                float val = acc[i][j][q] + x[off];
                x1v[i][j][q] = val;
                pss[i][q] += val * val;
            }
        }
    }
#pragma unroll
    for (int i = 0; i < 2; ++i)
#pragma unroll
        for (int q = 0; q < 4; ++q) {
            float p = pss[i][q];
            p += __shfl_xor(p, 1); p += __shfl_xor(p, 2);
            p += __shfl_xor(p, 4); p += __shfl_xor(p, 8);
            pss[i][q] = p;
        }
    if (l15 == 0) {
#pragma unroll
        for (int i = 0; i < 2; ++i)
#pragma unroll
            for (int q = 0; q < 4; ++q)
                ssbuf[wc * 64 + wr * 32 + i * 16 + lhi * 4 + q] = pss[i][q];
    }
    lgkm0_bar();
#pragma unroll
    for (int i = 0; i < 2; ++i)
#pragma unroll
        for (int q = 0; q < 4; ++q) {
            int rowl = wr * 32 + i * 16 + lhi * 4 + q;
            float ssum = ssbuf[rowl] + ssbuf[64 + rowl];
            float inv = 1.0f / (sqrtf(ssum * (1.0f / DIM_)) + 1e-8f);
#pragma unroll
            for (int j = 0; j < 4; ++j) {
                int n = wc * 64 + j * 16 + l15;
                *(short*)((char*)Xs + rowl * 256 + ((n * 2) ^ ((rowl & 7) << 4))) =
                    f2bf(x1v[i][j][q] * inv * ffn_s[n]);
            }
        }
    asm volatile("s_waitcnt vmcnt(0) lgkmcnt(0)" ::: "memory");
    __builtin_amdgcn_sched_barrier(0);
    __builtin_amdgcn_s_barrier();
    __builtin_amdgcn_sched_barrier(0);

    // ---------- FFN phases ----------
    f32x4 aout[2][4] = {};
    for (int p = 0; p < 8; ++p) {
        // GEMM1: this 64-col HID slice
        f32x4 a1[2][2] = {}, a2[2][2] = {};
#pragma unroll
        for (int ks = 0; ks < 4; ++ks) {
            bf16x8 af[2], b1f[2], b2f[2];
#pragma unroll
            for (int i = 0; i < 2; ++i) af[i] = frag_ld128(Xs, wr * 32 + i * 16 + l15, ks, lhi);
#pragma unroll
            for (int j = 0; j < 2; ++j) {
                b1f[j] = frag_ld128(W1s, wc * 32 + j * 16 + l15, ks, lhi);
                b2f[j] = frag_ld128(W2s, wc * 32 + j * 16 + l15, ks, lhi);
            }
#pragma unroll
            for (int i = 0; i < 2; ++i)
#pragma unroll
                for (int j = 0; j < 2; ++j) {
                    a1[i][j] = __builtin_amdgcn_mfma_f32_16x16x32_bf16(af[i], b1f[j], a1[i][j], 0, 0, 0);
                    a2[i][j] = __builtin_amdgcn_mfma_f32_16x16x32_bf16(af[i], b2f[j], a2[i][j], 0, 0, 0);
                }
        }
        // SwiGLU -> Hs
        int nn0 = p * 64;
#pragma unroll
        for (int i = 0; i < 2; ++i) {
            int mloc = wr * 32 + i * 16 + lhi * 4;
#pragma unroll
            for (int j = 0; j < 2; ++j) {
                int nloc = wc * 32 + j * 16 + l15;
                float bb1 = b1[nn0 + nloc], bb2 = b2[nn0 + nloc];
#pragma unroll
                for (int q = 0; q < 4; ++q) {
                    float u = a1[i][j][q] + bb1;
                    float w2v = a2[i][j][q] + bb2;
                    float hv = u / (1.0f + expf(-u)) * w2v;
                    int mq = mloc + q;
                    *(short*)((char*)Hs + mq * 128 + ((nloc * 2) ^ ((mq & 7) << 4))) = f2bf(hv);
                }
            }
        }
        lgkm0_bar();                 // Hs visible; W1s/W2s reads complete across block
        if (p < 7) stageW12(p + 1);  // prefetch under GEMM2
        // GEMM2: aout += h @ W3 slice
#pragma unroll
        for (int ks = 0; ks < 2; ++ks) {
            bf16x8 af[2], bfr[4];
#pragma unroll
            for (int i = 0; i < 2; ++i) af[i] = frag_ld(Hs, wr * 32 + i * 16 + l15, ks, lhi);
#pragma unroll
            for (int j = 0; j < 4; ++j) bfr[j] = frag_ld(W3s, wc * 64 + j * 16 + l15, ks, lhi);
#pragma unroll
            for (int i = 0; i < 2; ++i)
#pragma unroll
                for (int j = 0; j < 4; ++j)
                    aout[i][j] = __builtin_amdgcn_mfma_f32_16x16x32_bf16(af[i], bfr[j], aout[i][j], 0, 0, 0);
        }
        barrier_();
        if (p < 7) {
            stageW3(p + 1);
            WAIT_VMCNT(0);
            barrier_();
        }
    }
    // ---------- final: out = aout + x1 + b3 (fragment layouts match) ----------
#pragma unroll
    for (int i = 0; i < 2; ++i) {
        int gibase = m0 + wr * 32 + i * 16 + lhi * 4;
#pragma unroll
        for (int j = 0; j < 4; ++j) {
            int n = wc * 64 + j * 16 + l15;
            float bv = b3[n];
#pragma unroll
            for (int q = 0; q < 4; ++q) {
                size_t off = ((size_t)b * 512 + gibase + q) * 128 + n;
                out[off] = aout[i][j][q] + x1v[i][j][q] + bv;
            }
        }
    }
}

// ---- workspace layout (bytes) ----
constexpr size_t ALIGN_UP(size_t x) { return (x + 255) & ~(size_t)255; }
constexpr size_t SZ_RT   = ALIGN_UP((size_t)BN_ROWS * E_ * 4);         // f32
constexpr size_t SZ_A1   = ALIGN_UP((size_t)32 * 512 * 32 * 2);        // bf16
constexpr size_t SZ_A2   = ALIGN_UP((size_t)2 * 512 * 512 * 2);        // bf16
constexpr size_t SZ_XNT  = ALIGN_UP((size_t)B_ * 128 * 512 * 2);       // bf16
constexpr size_t SZ_YT   = ALIGN_UP((size_t)B_ * 128 * 1024 * 2);      // bf16
constexpr size_t SZ_WT   = ALIGN_UP((size_t)128 * 512 * 2);            // bf16 (each)

extern "C" void kernel_launch(void* const* d_in, const int* in_sizes, int n_in,
                              void* d_out, int out_size, void* d_ws, size_t ws_size,
                              hipStream_t stream) {
    const float* x      = (const float*)d_in[0];
    const float* bias   = (const float*)d_in[1];
    const float* attn_s = (const float*)d_in[2];
    const float* ffn_s  = (const float*)d_in[3];
    const float* Wr     = (const float*)d_in[4];
    const float* br     = (const float*)d_in[5];
    const float* E1     = (const float*)d_in[6];
    const float* E2     = (const float*)d_in[7];
    const float* lq1    = (const float*)d_in[8];
    const float* lk1    = (const float*)d_in[9];
    const float* lq2    = (const float*)d_in[10];
    const float* lk2    = (const float*)d_in[11];
    // d_in[12] = outer_lambda: unused (outer mixing matrix == identity)
    const float* W1     = (const float*)d_in[13];
    const float* b1     = (const float*)d_in[14];
    const float* W2     = (const float*)d_in[15];
    const float* b2     = (const float*)d_in[16];
    const float* W3     = (const float*)d_in[17];
    const float* b3     = (const float*)d_in[18];

    char* p = (char*)d_ws;
    float* rt   = (float*)p;            p += SZ_RT;
    short* A1nb = (short*)p;            p += SZ_A1;
    short* A2nb = (short*)p;            p += SZ_A2;
    short* xnT  = (short*)p;            p += SZ_XNT;
    short* YT   = (short*)p;            p += SZ_YT;
    short* W1T  = (short*)p;            p += SZ_WT;
    short* W2T  = (short*)p;            p += SZ_WT;
    short* W3T  = (short*)p;            p += SZ_WT;
    float* lam  = (float*)p;            p += 256;

    float* out_x   = (float*)d_out;
    float* out_idx = out_x + (size_t)BN_ROWS * DIM_;  // indices stored as float values

    float lam_init = 0.8f - 0.6f * expf(-0.3f);  // DEPTH = 1

    hipLaunchKernelGGL(k_misc, dim3(NMISC), dim3(256), 0, stream,
                       x, attn_s, Wr, br, bias, rt, out_idx, xnT,
                       E1, A1nb, E2, A2nb, W1, W2, W3, W1T, W2T, W3T,
                       lq1, lk1, lq2, lk2, lam_init, lam);
    hipLaunchKernelGGL(k_gemm_y, dim3(512), dim3(256), 0, stream, A2nb, xnT, YT);
    hipLaunchKernelGGL(k_attn_ffn, dim3(512), dim3(256), 0, stream,
                       A1nb, rt, YT, x, lam, ffn_s, W1T, b1, W2T, b2, W3T, b3, out_x);
}